// Round 1
// 195.891 us; speedup vs baseline: 1.0625x; 1.0625x over previous
//
#include <hip/hip_runtime.h>
#include <stdint.h>

#define NUM_B 128
#define NUM_P 8732
#define NUM_G 16
#define NUM_C 21
#define THR 0.5f
#define PB 35            // ceil(8732/256)
#define SEL_T 1024
#define SEL_W (SEL_T / 64)
#define RED_S 17         // padded stride for the iou transpose matrix
#define NV4 (NUM_P / 4)  // 2183 exact

struct Globals {
    unsigned int ticket;
};

__device__ __forceinline__ unsigned int f2u(float f) {
    unsigned int b = __float_as_uint(f);
    return (b & 0x80000000u) ? ~b : (b | 0x80000000u);
}
__device__ __forceinline__ float u2f(unsigned int u) {
    unsigned int b = (u & 0x80000000u) ? (u & 0x7FFFFFFFu) : ~u;
    return __uint_as_float(b);
}

// async global->LDS, 16B per lane; LDS dst = wave-uniform base + lane*16
__device__ __forceinline__ void gl_lds16(const float* gsrc, float* ldst) {
    __builtin_amdgcn_global_load_lds(
        (__attribute__((address_space(1))) void*)gsrc,
        (__attribute__((address_space(3))) void*)ldst,
        16, 0, 0);
}

// IoU of prior box vs all 16 gts. Single source of truth: fused main pass and
// select's delta-patch both call this so matches are bit-identical.
__device__ __forceinline__ void match16(float4 pr, const float (*tg)[11],
                                        float* iou, float& ov, int& j0) {
    float bx1 = pr.x - pr.z * 0.5f, by1 = pr.y - pr.w * 0.5f;
    float bx2 = pr.x + pr.z * 0.5f, by2 = pr.y + pr.w * 0.5f;
    float areaB = (bx2 - bx1) * (by2 - by1);
    ov = -1.0f; j0 = 0;
    #pragma unroll
    for (int j = 0; j < NUM_G; ++j) {
        float ax1 = tg[j][0], ay1 = tg[j][1], ax2 = tg[j][2], ay2 = tg[j][3];
        float dx = fminf(ax2, bx2) - fmaxf(ax1, bx1);
        float dy = fminf(ay2, by2) - fmaxf(ay1, by1);
        dx = fmaxf(dx, 0.f); dy = fmaxf(dy, 0.f);
        float inter = dx * dy;
        float uni = (ax2 - ax1) * (ay2 - ay1) + areaB - inter;
        float v = inter * __builtin_amdgcn_rcpf(uni);   // v_rcp_f32 (fast)
        iou[j] = v;
        if (v > ov) { ov = v; j0 = j; }   // strict > => first-index argmax
    }
}

// smooth-L1 sum for prior (pr, loc row ld) vs target row tgj (11 floats)
__device__ __forceinline__ float sl1_sum(const float* __restrict__ ld,
                                         float4 pr, const float* tgj) {
    float t[10];
    t[0] = ((tgj[0] + tgj[2]) * 0.5f - pr.x) / (0.1f * pr.z);
    t[1] = ((tgj[1] + tgj[3]) * 0.5f - pr.y) / (0.1f * pr.w);
    t[2] = __logf((tgj[2] - tgj[0]) / pr.z) / 0.2f;
    t[3] = __logf((tgj[3] - tgj[1]) / pr.w) / 0.2f;
    t[4] = __logf(tgj[4] / pr.z + 0.1f) / 0.2f;
    t[5] = __logf(tgj[5] / pr.w + 0.1f) / 0.2f;
    t[6] = __logf(tgj[6] / pr.z + 0.1f) / 0.2f;
    t[7] = __logf(tgj[7] / pr.w + 0.1f) / 0.2f;
    t[8] = (tgj[8] - pr.x) / (0.1f * pr.z);
    t[9] = (tgj[9] - pr.y) / (0.1f * pr.w);
    float s = 0.f;
    #pragma unroll
    for (int d = 0; d < 10; ++d) {
        float df = ld[d] - t[d];
        float ad = fabsf(df);
        s += (ad < 1.f) ? 0.5f * df * df : (ad - 0.5f);
    }
    return s;
}

// single-pass LSE (logits ~ N(0,1): no overflow risk)
__device__ __forceinline__ float lse21(const float* cv) {
    float s = 0.f;
    #pragma unroll
    for (int c = 0; c < NUM_C; ++c) s += __expf(cv[c]);
    return __logf(s);
}

// ---------------------------------------------------------------- fused match + loss
// Outputs are per-block SLOTS (written unconditionally) so no init kernel is
// needed: pbp[b][bx][g] packed (maxiou<<32 | ~idx), pll/ppc/pcnt[b][bx].
// lcu = f2u(lc) pre-converted for select's radix. Ticket zeroed by block (0,0).
__global__ void __launch_bounds__(256) fused_kernel(
        const float* __restrict__ loc_data,
        const float* __restrict__ conf_data,
        const float* __restrict__ priors,
        const float* __restrict__ targets,
        unsigned int* __restrict__ lcu,
        unsigned long long* __restrict__ pbp,
        float* __restrict__ pll,
        float* __restrict__ ppc,
        unsigned int* __restrict__ pcnt,
        Globals* __restrict__ g) {
    int b    = blockIdx.y;
    int bx   = blockIdx.x;
    int tid  = threadIdx.x;
    int base = bx * 256;
    int i    = base + tid;
    bool valid = (i < NUM_P);
    int ic   = valid ? i : (NUM_P - 1);
    int lane = tid & 63;
    int wave = tid >> 6;

    if (b == 0 && bx == 0 && tid == 0) g->ticket = 0u;  // published at kernel end

    __shared__ float tg[NUM_G][11];
    __shared__ float sconf[256 * NUM_C];       // 21504 B; re-used as red after B2
    __shared__ unsigned int gmaxu[NUM_G];
    __shared__ unsigned int sidx[NUM_G];
    __shared__ float wll[4], wpc[4];
    __shared__ unsigned int wcnt[4];

    // ---- stage conf (async 1KiB wave-chunks on full blocks)
    const float* cbase = conf_data + ((size_t)b * NUM_P + base) * NUM_C;
    int cnt_p = NUM_P - base; if (cnt_p > 256) cnt_p = 256;
    if (cnt_p == 256) {
        #pragma unroll
        for (int c = 0; c < 21; ++c)
            if ((c & 3) == wave)
                gl_lds16(cbase + (c << 8) + lane * 4, &sconf[c << 8]);
    } else {
        int tot = cnt_p * NUM_C;
        for (int x = tid; x < tot; x += 256) sconf[x] = cbase[x];
    }
    if (tid < NUM_G * 11) {
        int j = tid / 11, d = tid - j * 11;
        tg[j][d] = targets[(size_t)(b * NUM_G + j) * 11 + d];
    }
    if (tid < NUM_G) { gmaxu[tid] = 0u; sidx[tid] = 0xFFFFFFFFu; }
    __syncthreads();   // B1: tg + conf resident (barrier drains vmcnt)

    // ---- matching (registers)
    float4 pr = ((const float4*)priors)[ic];
    float iou[NUM_G]; float ov; int j0;
    match16(pr, tg, iou, ov, j0);
    #pragma unroll
    for (int j = 0; j < NUM_G; ++j)
        if (!valid) iou[j] = -1.0f;            // invalid lanes can't win

    // ---- loss terms (consume sconf)
    float ll = 0.f, pc = 0.f; unsigned int cnt = 0u;
    if (valid) {
        bool pos = ov >= THR;
        int conf_t = pos ? ((int)tg[j0][10] + 1) : 0;
        const float* cv = &sconf[tid * NUM_C];   // gcd(21,32)=1 -> conflict-free
        float lse = lse21(cv);
        float lca = lse - cv[conf_t];
        lcu[(size_t)b * NUM_P + i] = f2u(pos ? 0.f : lca);
        if (pos) {
            cnt = 1u; pc = lca;
            ll = sl1_sum(loc_data + ((size_t)b * NUM_P + i) * 10, pr, tg[j0]);
        }
    }
    for (int off = 32; off > 0; off >>= 1) {
        ll  += __shfl_down(ll, (unsigned)off, 64);
        pc  += __shfl_down(pc, (unsigned)off, 64);
        cnt += __shfl_down(cnt, (unsigned)off, 64);
    }
    if ((tid & 63) == 0) { wll[wave] = ll; wpc[wave] = pc; wcnt[wave] = cnt; }
    __syncthreads();   // B2: sconf fully consumed; wave partials visible

    // ---- iou transpose into the SAME buffer (aliased)
    unsigned int* red = (unsigned int*)sconf;   // 256*17*4 = 17408 <= 21504
    #pragma unroll
    for (int j = 0; j < NUM_G; ++j)
        red[tid * RED_S + j] = f2u(iou[j]);     // 17t mod 32 bijective -> 2-way free
    __syncthreads();   // B3: red ready

    // ---- per-gt block max: slice reduce + wave fold + 1 atomic per (wave,gt)
    {
        int gg = tid & 15, s = tid >> 4;
        unsigned int mx = 0u;
        #pragma unroll
        for (int k = 0; k < 16; ++k) {
            unsigned int v = red[(s * 16 + k) * RED_S + gg];
            mx = (v > mx) ? v : mx;
        }
        unsigned int o;
        o = (unsigned int)__shfl_xor((int)mx, 16, 64); mx = (o > mx) ? o : mx;
        o = (unsigned int)__shfl_xor((int)mx, 32, 64); mx = (o > mx) ? o : mx;
        if (lane < 16) atomicMax(&gmaxu[gg], mx);
    }
    __syncthreads();   // B4: gmaxu final

    // ---- first-index tie-break (winners are rare)
    #pragma unroll
    for (int j = 0; j < NUM_G; ++j)
        if (f2u(iou[j]) == gmaxu[j]) atomicMin(&sidx[j], (unsigned int)i);
    __syncthreads();   // B5: sidx final

    if (tid < NUM_G) {
        unsigned long long pk = ((unsigned long long)gmaxu[tid] << 32) |
                                (unsigned long long)(0xFFFFFFFFu - sidx[tid]);
        pbp[((size_t)b * PB + bx) * NUM_G + tid] = pk;   // coalesced u64 slot store
    }
    if (tid == 0) {
        float a = 0.f, c = 0.f; unsigned int n = 0u;
        #pragma unroll
        for (int w = 0; w < 4; ++w) { a += wll[w]; c += wpc[w]; n += wcnt[w]; }
        int s = b * PB + bx;
        pll[s] = a; ppc[s] = c; pcnt[s] = n;
    }
    // kernel boundary = global barrier; select sees all slot stores completed.
}

// ---------------------------------------------------------------- select: slot-reduce + override delta-patch + top-k radix select
__global__ void __launch_bounds__(SEL_T) select_kernel(
        const float* __restrict__ loc_data,
        const float* __restrict__ conf_data,
        const float* __restrict__ priors,
        const float* __restrict__ targets,
        const unsigned int* __restrict__ lcu,
        const unsigned long long* __restrict__ pbp,
        const float* __restrict__ pll,
        const float* __restrict__ ppc,
        const unsigned int* __restrict__ pcnt,
        float* __restrict__ row_ll_f,
        unsigned int* __restrict__ row_pos_f,
        float* __restrict__ row_loss_c,
        Globals* __restrict__ g,
        float* __restrict__ out) {
    int b    = blockIdx.x;
    int tid  = threadIdx.x;
    int wv   = tid >> 6;
    int lane = tid & 63;

    __shared__ __align__(16) unsigned int su[NUM_P];       // 34928 B
    __shared__ unsigned int whist[SEL_W * 257];            // 16448 B
    __shared__ __align__(16) unsigned int stot[256];
    __shared__ float tg[NUM_G][11];
    __shared__ float wsum[SEL_W];
    __shared__ unsigned int s_prefix;
    __shared__ int s_kk;
    __shared__ int s_last;
    __shared__ float s_dll, s_dpc;
    __shared__ int s_dcnt, s_np;
    __shared__ int s_patch[NUM_G];
    __shared__ float s_sll, s_spc;
    __shared__ unsigned int s_scnt;

    if (tid == 0) { s_dll = 0.f; s_dpc = 0.f; s_dcnt = 0; s_np = 0; }
    if (tid < NUM_G * 11) {
        int j = tid / 11, d = tid - j * 11;
        tg[j][d] = targets[(size_t)(b * NUM_G + j) * 11 + d];
    }
    __syncthreads();   // b0: tg + scalars visible

    const uint4* lp4 = (const uint4*)(lcu + (size_t)b * NUM_P);  // 16B aligned

    if (wv == 0) {
        // ---- per-gt max over 35 block slots, in registers (no block barrier).
        // Lane l handles gt (l&15); the 16 u64s per slot are one 128B line.
        int j = tid & 15;
        unsigned long long mx = 0ull;
        for (int pb = 0; pb < PB; ++pb) {
            unsigned long long v = pbp[((size_t)b * PB + pb) * NUM_G + j];
            mx = (v > mx) ? v : mx;
        }
        int ii = (int)(0xFFFFFFFFu - (unsigned int)(mx & 0xFFFFFFFFull));
        bool winner = (tid < NUM_G);
        #pragma unroll
        for (int j2 = 0; j2 < NUM_G; ++j2) {
            int o = __shfl(ii, j2, 64);
            if (j2 > j && o == ii) winner = false;   // later j wins duplicates
        }
        // ---- override delta-patch (overlaps with staging by waves 1..15)
        if (winner) {
            float4 prr = ((const float4*)priors)[ii];
            float io2[NUM_G]; float ov0; int jj0;
            match16(prr, tg, io2, ov0, jj0);         // bit-identical to fused
            bool pos0 = ov0 >= THR;
            const float* cd = conf_data + ((size_t)b * NUM_P + ii) * NUM_C;
            float lse = lse21(cd);
            const float* ld = loc_data + ((size_t)b * NUM_P + ii) * 10;
            float lca_new = lse - cd[(int)tg[tid][10] + 1];
            float ll_new  = sl1_sum(ld, prr, tg[tid]);
            if (pos0) {
                float lca_old = lse - cd[(int)tg[jj0][10] + 1];
                float ll_old  = sl1_sum(ld, prr, tg[jj0]);
                atomicAdd(&s_dpc, lca_new - lca_old);
                atomicAdd(&s_dll, ll_new - ll_old);
            } else {
                atomicAdd(&s_dpc, lca_new);
                atomicAdd(&s_dll, ll_new);
                atomicAdd(&s_dcnt, 1);
                int e = atomicAdd(&s_np, 1);
                s_patch[e] = ii;
            }
        }
    } else {
        if (wv == 1) {
            // ---- row partial sums (35 slots) on wave 1, then it joins staging
            float a = 0.f, c = 0.f; unsigned int n = 0u;
            if (lane < PB) {
                a = pll[b * PB + lane];
                c = ppc[b * PB + lane];
                n = pcnt[b * PB + lane];
            }
            for (int off = 32; off > 0; off >>= 1) {
                a += __shfl_down(a, (unsigned)off, 64);
                c += __shfl_down(c, (unsigned)off, 64);
                n += __shfl_down(n, (unsigned)off, 64);
            }
            if (lane == 0) { s_sll = a; s_spc = c; s_scnt = n; }
        }
        // ---- stage pre-converted lc keys as uint4 (waves 1..15, 960 threads)
        for (int q = tid - 64; q < NV4; q += SEL_T - 64)
            ((uint4*)su)[q] = lp4[q];
    }
    __syncthreads();   // b1: su staged + patches + row sums done

    if (tid < s_np) su[s_patch[tid]] = 0x80000000u;   // f2u(0): patched positives leave neg pool
    __syncthreads();   // b2

    int npos = (int)s_scnt + s_dcnt;
    int k = 3 * npos; if (k > NUM_P - 1) k = NUM_P - 1;

    float negsum = 0.f;
    if (k > 0) {
        if (tid == 0) { s_prefix = 0u; s_kk = k; }
        __syncthreads();

        for (int pass = 0; pass < 4; ++pass) {
            int shift = 24 - 8 * pass;
            for (int x = tid; x < SEL_W * 257; x += SEL_T) whist[x] = 0u;
            __syncthreads();
            unsigned int prefix = s_prefix;
            int kkc = s_kk;
            unsigned int hmask = (pass == 0) ? 0u : (0xFFFFFFFFu << (shift + 8));
            for (int q = tid; q < NV4; q += SEL_T) {
                uint4 u4 = ((const uint4*)su)[q];
                if ((u4.x & hmask) == prefix) atomicAdd(&whist[wv * 257 + ((u4.x >> shift) & 255u)], 1u);
                if ((u4.y & hmask) == prefix) atomicAdd(&whist[wv * 257 + ((u4.y >> shift) & 255u)], 1u);
                if ((u4.z & hmask) == prefix) atomicAdd(&whist[wv * 257 + ((u4.z >> shift) & 255u)], 1u);
                if ((u4.w & hmask) == prefix) atomicAdd(&whist[wv * 257 + ((u4.w >> shift) & 255u)], 1u);
            }
            __syncthreads();
            if (tid < 256) {
                unsigned int t = 0;
                #pragma unroll
                for (int w = 0; w < SEL_W; ++w) t += whist[w * 257 + tid];
                stot[tid] = t;
            }
            __syncthreads();
            // single-wave suffix scan: lane l owns buckets 4l..4l+3 (b128 read)
            if (tid < 64) {
                uint4 v4 = ((const uint4*)stot)[tid];
                unsigned int s3 = v4.w, s2 = v4.z + s3, s1 = v4.y + s2, s0 = v4.x + s1;
                unsigned int T = s0, suf = T;
                #pragma unroll
                for (int off = 1; off < 64; off <<= 1) {
                    unsigned int nn = (unsigned int)__shfl_down((int)suf, off, 64);
                    if (tid + off < 64) suf += nn;
                }
                unsigned int higher = suf - T;            // suffix of lanes > l
                unsigned int Si[4] = { higher + s0, higher + s1, higher + s2, higher + s3 };
                unsigned int Vi[4] = { v4.x, v4.y, v4.z, v4.w };
                #pragma unroll
                for (int t = 0; t < 4; ++t) {
                    int Sself = (int)Si[t];
                    int Snext = Sself - (int)Vi[t];
                    if (Snext < kkc && kkc <= Sself) {    // unique (t,lane) hits
                        s_prefix = prefix | ((unsigned int)(4 * tid + t) << shift);
                        s_kk = kkc - Snext;
                    }
                }
            }
            __syncthreads();
        }

        unsigned int Tu = s_prefix;
        int m = s_kk;
        float local = 0.f;
        for (int q = tid; q < NV4; q += SEL_T) {
            uint4 u4 = ((const uint4*)su)[q];
            if (u4.x > Tu) local += u2f(u4.x);
            if (u4.y > Tu) local += u2f(u4.y);
            if (u4.z > Tu) local += u2f(u4.z);
            if (u4.w > Tu) local += u2f(u4.w);
        }
        for (int off = 32; off > 0; off >>= 1)
            local += __shfl_down(local, (unsigned)off, 64);
        if (lane == 0) wsum[wv] = local;
        __syncthreads();
        if (tid == 0) {
            float ssum = 0.f;
            #pragma unroll
            for (int w = 0; w < SEL_W; ++w) ssum += wsum[w];
            negsum = ssum + (float)m * u2f(Tu);
        }
    }

    if (tid == 0) {
        row_ll_f[b]   = s_sll + s_dll;
        row_pos_f[b]  = (unsigned int)npos;
        row_loss_c[b] = (s_spc + s_dpc) + negsum;
        __threadfence();
        unsigned int t = atomicAdd(&g->ticket, 1u);
        s_last = (t == NUM_B - 1) ? 1 : 0;
    }
    __syncthreads();

    if (s_last) {
        float l = 0.f, c = 0.f, n = 0.f;
        if (tid < NUM_B) {
            l = atomicAdd((float*)&row_ll_f[tid], 0.f);
            c = atomicAdd((float*)&row_loss_c[tid], 0.f);
            n = (float)atomicAdd((unsigned int*)&row_pos_f[tid], 0u);
        }
        for (int off = 32; off > 0; off >>= 1) {
            l += __shfl_down(l, (unsigned)off, 64);
            c += __shfl_down(c, (unsigned)off, 64);
            n += __shfl_down(n, (unsigned)off, 64);
        }
        __shared__ float fl[2], fc[2], fn[2];
        if (tid < NUM_B && lane == 0) { fl[wv] = l; fc[wv] = c; fn[wv] = n; }
        __syncthreads();
        if (tid == 0) {
            float L = fl[0] + fl[1], C = fc[0] + fc[1], N = fn[0] + fn[1];
            out[0] = L / N;
            out[1] = C / N;
        }
    }
}

extern "C" void kernel_launch(void* const* d_in, const int* in_sizes, int n_in,
                              void* d_out, int out_size, void* d_ws, size_t ws_size,
                              hipStream_t stream) {
    const float* loc_data  = (const float*)d_in[0];
    const float* conf_data = (const float*)d_in[1];
    const float* priors    = (const float*)d_in[2];
    const float* targets   = (const float*)d_in[3];
    float* out = (float*)d_out;

    char* ws = (char*)d_ws;
    size_t off = 0;
    unsigned int* lcu = (unsigned int*)(ws + off);
    off += (size_t)NUM_B * NUM_P * sizeof(unsigned int);
    unsigned long long* pbp = (unsigned long long*)(ws + off);
    off += (size_t)NUM_B * PB * NUM_G * sizeof(unsigned long long);
    float* pll = (float*)(ws + off); off += (size_t)NUM_B * PB * sizeof(float);
    float* ppc = (float*)(ws + off); off += (size_t)NUM_B * PB * sizeof(float);
    unsigned int* pcnt = (unsigned int*)(ws + off); off += (size_t)NUM_B * PB * sizeof(unsigned int);
    float* row_ll_f = (float*)(ws + off); off += NUM_B * sizeof(float);
    unsigned int* row_pos_f = (unsigned int*)(ws + off); off += NUM_B * sizeof(unsigned int);
    float* row_loss_c = (float*)(ws + off); off += NUM_B * sizeof(float);
    Globals* g = (Globals*)(ws + off); off += sizeof(Globals);

    // 2 launches: init folded away (slot outputs need no zeroing; fused block
    // (0,0) zeroes the ticket for select's last-block detection).
    fused_kernel<<<dim3(PB, NUM_B), 256, 0, stream>>>(
        loc_data, conf_data, priors, targets, lcu, pbp, pll, ppc, pcnt, g);
    select_kernel<<<NUM_B, SEL_T, 0, stream>>>(
        loc_data, conf_data, priors, targets,
        lcu, pbp, pll, ppc, pcnt,
        row_ll_f, row_pos_f, row_loss_c, g, out);
}